// Round 19
// baseline (212.913 us; speedup 1.0000x reference)
//
#include <hip/hip_runtime.h>
#include <hip/hip_bf16.h>
#include <math.h>

// DualTimeConstantAdaptation: y = full cross-correlation(softplus(x), kern),
// kern[k] = (a1^k + a2^k)/S, K=4800.
// Infinite-scan difference form: G_c(s) = a_c*G_c(s+1) + w[s] (reverse scan),
//   y[t] = (G1(s) + G2(s) - c2*G2(s+K)) / S,  s = t-(K-1), c2 = a2^K.
// Ghosts cancel exactly; G2(s+K) via 5-deep bf16 register ring.
// R16: coalesced loads (lane+64*i, 15x fewer L1 transactions) + wave-private
// LDS transpose. R18 FIX: stage() is CROSS-LANE LDS communication -- per-
// thread alias analysis lets the compiler reorder ds_reads above ds_writes
// (absmax 0.0039 -> 0.0586). Fence: memory clobber + s_waitcnt lgkmcnt(0) +
// sched_barrier(0) between write and read phases (HW DS pipe is in-order per
// wave; the fence is for the COMPILER).

#define TT    48000
#define KK    4800
#define OUTT  52799
#define SEGS  11                 // wave-segments per channel
#define E     15                 // elements per lane
#define TILE  960                // 64 lanes * E
#define NSTT  5                  // store tiles per segment
#define LSEG  (NSTT * TILE)      // 4800 stored positions per segment
#define NT    10                 // traversal tiles = NSTT + KK/TILE
#define RD    5                  // ring depth = KK/TILE
#define SMIN  (TT - SEGS * LSEG) // -4800
#define NEGPAD (-1.0e30f)        // softplus(NEGPAD) == 0 exactly

__device__ __forceinline__ float softplus_fast(float v) {
    // log(1+e^v) via v_exp/v_log; randn input -> no overflow; exp(-1e30)=0
    return __logf(1.0f + __expf(v));
}

__device__ __forceinline__ unsigned pack_bf2(float a, float b) {
    union { __hip_bfloat16 h; unsigned short u; } ca, cb;
    ca.h = __float2bfloat16(a);
    cb.h = __float2bfloat16(b);
    return (unsigned)ca.u | ((unsigned)cb.u << 16);
}

__device__ __forceinline__ float2 unpack_bf2(unsigned v) {
    union { unsigned u; float f; } fa, fb;
    fa.u = (v & 0xffffu) << 16;
    fb.u = v & 0xffff0000u;
    return make_float2(fa.f, fb.f);
}

// COALESCED loads of tile [sLow, sLow+TILE): lane reads sLow + lane + 64*i.
// Each instr covers 256 contiguous bytes (4 cache lines) across the wave.
__device__ __forceinline__ void load_coal(float (&g)[E], const float* __restrict__ xc,
                                          int sLow, int lane) {
    if (sLow >= 0 && sLow + TILE <= TT) {
        #pragma unroll
        for (int i = 0; i < E; ++i) g[i] = xc[sLow + lane + 64 * i];
    } else {
        #pragma unroll
        for (int i = 0; i < E; ++i) {
            const int ss = sLow + lane + 64 * i;
            g[i] = (ss >= 0 && ss < TT) ? xc[ss] : NEGPAD;
        }
    }
}

// wave-private LDS transpose: coalesced-order regs -> lane-contiguous cur.
// ds_write stride 64 (conflict-free); ds_read lane*15+j (2-way alias, free).
// CROSS-LANE data flow: hardware DS pipe is in-order within a wave, but the
// COMPILER must be fenced (per-thread alias analysis sees disjoint sets and
// will reorder reads above writes -- R16's correctness bug).
__device__ __forceinline__ void stage(float* __restrict__ wlds,
                                      const float (&g)[E], float (&c)[E], int lane) {
    asm volatile("" ::: "memory");   // WAR: don't hoist writes above prior reads
    #pragma unroll
    for (int i = 0; i < E; ++i) wlds[lane + 64 * i] = g[i];
    asm volatile("s_waitcnt lgkmcnt(0)" ::: "memory");  // RAW: writes before reads
    __builtin_amdgcn_sched_barrier(0);                  // rule #18: pin the order
    #pragma unroll
    for (int j = 0; j < E; ++j) c[j] = wlds[lane * E + j];
    asm volatile("" ::: "memory");
}

template <int SLOT, bool STORES, bool PREF>
__device__ __forceinline__ void tile_step(
    int tau, int segTop, int lane,
    const float* __restrict__ xc, float* __restrict__ yc,
    float* __restrict__ wlds,
    float a1, float a2, float c2, float invS,
    const float (&p1)[E + 1], const float (&p2)[E + 1],
    float P1, float P2,
    float& pc1, float& pc2,
    unsigned (&ring)[RD][8],
    float (&cur)[E], float (&greg)[E])
{
    const int sLow = segTop - (tau + 1) * TILE;
    const int s0 = sLow + E * lane;

    // ISSUE-EARLY: next tile's coalesced loads fly during this tile's compute
    if (PREF) load_coal(greg, xc, sLow - TILE, lane);

    float xs[E];
    #pragma unroll
    for (int j = 0; j < E; ++j) xs[j] = softplus_fast(cur[j]);

    // local zero-init suffix scans over the lane's E positions
    float L1[E], L2[E];
    float h1 = 0.0f, h2 = 0.0f;
    #pragma unroll
    for (int j = E - 1; j >= 0; --j) {
        h1 = fmaf(a1, h1, xs[j]); L1[j] = h1;
        h2 = fmaf(a2, h2, xs[j]); L2[j] = h2;
    }

    // wave-level suffix scan of lane aggregates (decay A_c = a_c^E = p[E])
    float sc1 = L1[0], sc2 = L2[0];
    float f1 = p1[E], f2 = p2[E];
    #pragma unroll
    for (int d = 1; d < 64; d <<= 1) {
        float v1 = __shfl_down(sc1, d);
        float v2 = __shfl_down(sc2, d);
        if (lane + d >= 64) { v1 = 0.0f; v2 = 0.0f; }
        sc1 = fmaf(f1, v1, sc1);
        sc2 = fmaf(f2, v2, sc2);
        f1 *= f1; f2 *= f2;
    }
    // G at this lane's lowest position (carry folded via P = a^(TILE - E*lane))
    const float S1 = fmaf(P1, pc1, sc1);
    const float S2 = fmaf(P2, pc2, sc2);
    // carry INTO this lane = G at s0+E (lane+1's S; lane 63 <- tile carry)
    float cin1 = __shfl_down(S1, 1);
    float cin2 = __shfl_down(S2, 1);
    if (lane == 63) { cin1 = pc1; cin2 = pc2; }
    // carry for the next (lower) tile = G at sLow (lane 0's S)
    pc1 = __shfl(S1, 0);
    pc2 = __shfl(S2, 0);

    // per-element slow-chain values G2(s0+j)
    float g2v[16];
    #pragma unroll
    for (int j = 0; j < E; ++j) g2v[j] = fmaf(p2[E - j], cin2, L2[j]);
    g2v[15] = 0.0f;

    if (STORES) {
        // ring slot currently holds G2 of tile tau-RD (positions s0+KK)
        float old[16];
        #pragma unroll
        for (int p = 0; p < 8; ++p) {
            const float2 f = unpack_bf2(ring[SLOT][p]);
            old[2 * p] = f.x; old[2 * p + 1] = f.y;
        }
        const int t0 = s0 + (KK - 1);
        float out[E];
        #pragma unroll
        for (int j = 0; j < E; ++j) {
            const float g1 = fmaf(p1[E - j], cin1, L1[j]);
            out[j] = (g1 + g2v[j] - c2 * old[j]) * invS;
        }
        if (t0 >= 0) {
            #pragma unroll
            for (int j = 0; j < E; ++j) yc[t0 + j] = out[j];
        } else {
            #pragma unroll
            for (int j = 0; j < E; ++j) if (t0 + j >= 0) yc[t0 + j] = out[j];
        }
    }

    // overwrite slot with current tile's G2 (consumed at tau+RD)
    #pragma unroll
    for (int p = 0; p < 8; ++p)
        ring[SLOT][p] = pack_bf2(g2v[2 * p], g2v[2 * p + 1]);

    // WRITE-LATE: vmcnt-wait lands here (after compute); stage next tile
    // through wave-private LDS into lane-contiguous cur
    if (PREF) stage(wlds, greg, cur, lane);
}

__global__ __launch_bounds__(256) void dtca_ring_kernel(
    const float* __restrict__ x, float* __restrict__ y,
    float a1, float a2, float c2, float invS, int nch)
{
    __shared__ float lds[4][TILE];

    const int wslot = threadIdx.x >> 6;
    const int wid  = blockIdx.x * 4 + wslot;               // global wave-segment id
    const int lane = threadIdx.x & 63;
    const int ch   = wid / SEGS;
    const int seg  = wid - ch * SEGS;
    if (ch >= nch) return;

    float* __restrict__ wlds = lds[wslot];
    const float* __restrict__ xc = x + (size_t)ch * TT;
    float* __restrict__ yc       = y + (size_t)ch * OUTT;

    const int segLo  = SMIN + seg * LSEG;
    const int segTop = segLo + NT * TILE;

    float p1[E + 1], p2[E + 1];
    p1[0] = 1.0f; p2[0] = 1.0f;
    #pragma unroll
    for (int k = 1; k <= E; ++k) { p1[k] = p1[k - 1] * a1; p2[k] = p2[k - 1] * a2; }
    const float P1 = __powf(a1, (float)(TILE - E * lane));
    const float P2 = __powf(a2, (float)(TILE - E * lane));

    unsigned ring[RD][8];
    #pragma unroll
    for (int r = 0; r < RD; ++r)
        #pragma unroll
        for (int p = 0; p < 8; ++p) ring[r][p] = 0u;

    float pc1 = 0.0f, pc2 = 0.0f;
    float cur[E], greg[E];

    // preload tile 0 (coalesced + LDS transpose)
    load_coal(greg, xc, segTop - TILE, lane);
    stage(wlds, greg, cur, lane);

    #define TSTEP(SL, ST, PF, TAU) \
        tile_step<SL, ST, PF>(TAU, segTop, lane, xc, yc, wlds, a1, a2, c2, invS, \
                              p1, p2, P1, P2, pc1, pc2, ring, cur, greg)

    // warm-up tiles: cover [segLo+LSEG, segTop) = K positions, no stores
    TSTEP(0, false, true, 0);
    TSTEP(1, false, true, 1);
    TSTEP(2, false, true, 2);
    TSTEP(3, false, true, 3);
    TSTEP(4, false, true, 4);
    // store tiles: cover [segLo, segLo+LSEG)
    TSTEP(0, true, true, 5);
    TSTEP(1, true, true, 6);
    TSTEP(2, true, true, 7);
    TSTEP(3, true, true, 8);
    TSTEP(4, true, false, 9);
    #undef TSTEP
}

extern "C" void kernel_launch(void* const* d_in, const int* in_sizes, int n_in,
                              void* d_out, int out_size, void* d_ws, size_t ws_size,
                              hipStream_t stream) {
    const float* x = (const float*)d_in[0];
    float* y = (float*)d_out;

    const int nelem = in_sizes[0];
    const int nch   = nelem / TT;      // B*C = 512

    const double a1d = exp(-1.0 / 32.0);
    const double a2d = exp(-1.0 / 960.0);
    const double c1d = exp(-4800.0 / 32.0);   // ~7e-66 -> 0 in fp32
    const double c2d = exp(-4800.0 / 960.0);  // e^-5
    const double S   = (1.0 - c1d) / (1.0 - a1d) + (1.0 - c2d) / (1.0 - a2d);

    const int nwaveseg = nch * SEGS;                 // 5632
    const int blocks   = (nwaveseg + 3) / 4;         // 1408
    dtca_ring_kernel<<<blocks, 256, 0, stream>>>(
        x, y, (float)a1d, (float)a2d, (float)c2d, (float)(1.0 / S), nch);
}